// Round 19
// baseline (165407.715 us; speedup 1.0000x reference)
//
#include <hip/hip_runtime.h>
#include <math.h>

#define CIN 256
#define K9  2304
#define TLW 16
#define TLH 8
#define LIS 22
#define TAU 3e-4f
#define NSLOT 64
#define SLOT_DBL (130 * 256)          // 81*256 + 49*256 doubles per slot

// ---------------------------------------------------------------------------
// PROVEN generic conv (R4/R8/R11): 64co x (16x8)px, 256 thr, 8co x 4px/thread.
// fp32-only instantiations now.
// ---------------------------------------------------------------------------
template<typename TI, typename TA, int CH, bool RELU>
__global__ __launch_bounds__(256, 2) void conv_tile(
    const TI* __restrict__ in, const float* __restrict__ wgt,
    const float* __restrict__ bias, TA* __restrict__ out,
    int H, int W, int C_out)
{
    const int NCH = CIN / CH;
    const int tilesX = (W + TLW - 1) / TLW;
    const int tx = (blockIdx.x % tilesX) * TLW;
    const int ty = (blockIdx.x / tilesX) * TLH;
    const int b  = blockIdx.y;
    const int co0 = blockIdx.z * 64;
    const int tid = threadIdx.x;
    const int tco = (tid >> 5) * 8;
    const int tpx = tid & 31;
    const int prow = tpx >> 2;
    const int pcol = (tpx & 3) * 4;

    __shared__ __align__(16) TA lw[CH * 9 * 64];
    __shared__ __align__(16) TA li[CH * 10 * LIS];

    TA acc[8][4];
    #pragma unroll
    for (int c = 0; c < 8; ++c)
        #pragma unroll
        for (int j = 0; j < 4; ++j) acc[c][j] = (TA)0;

    const int coLim = min(64, C_out - co0);

    for (int ch = 0; ch < NCH; ++ch) {
        const int ci0 = ch * CH;
        for (int idx = tid; idx < CH * 9 * 64; idx += 256) {
            int r  = idx >> 6;
            int co = idx & 63;
            TA v = (TA)0;
            if (co < coLim)
                v = (TA)wgt[(size_t)(co0 + co) * (CIN * 9) + (size_t)ci0 * 9 + r];
            lw[idx] = v;
        }
        for (int idx = tid; idx < CH * 10 * LIS; idx += 256) {
            int ci = idx / (10 * LIS);
            int rr = idx % (10 * LIS);
            int row = rr / LIS, col = rr % LIS;
            TA v = (TA)0;
            int iy = ty + row - 1, ix = tx + col - 1;
            if (col < TLW + 2 && iy >= 0 && iy < H && ix >= 0 && ix < W)
                v = (TA)in[(((size_t)b * CIN + ci0 + ci) * H + iy) * W + ix];
            li[idx] = v;
        }
        __syncthreads();
        #pragma unroll
        for (int ci = 0; ci < CH; ++ci) {
            #pragma unroll
            for (int ky = 0; ky < 3; ++ky) {
                const TA* ip = &li[ci * 10 * LIS + (prow + ky) * LIS + pcol];
                TA ir[6];
                #pragma unroll
                for (int t = 0; t < 6; ++t) ir[t] = ip[t];
                #pragma unroll
                for (int kx = 0; kx < 3; ++kx) {
                    const TA* wp = &lw[(ci * 9 + ky * 3 + kx) * 64 + tco];
                    TA wv[8];
                    #pragma unroll
                    for (int c = 0; c < 8; ++c) wv[c] = wp[c];
                    TA x0 = ir[kx], x1 = ir[kx + 1], x2 = ir[kx + 2], x3 = ir[kx + 3];
                    #pragma unroll
                    for (int c = 0; c < 8; ++c) {
                        acc[c][0] += wv[c] * x0;
                        acc[c][1] += wv[c] * x1;
                        acc[c][2] += wv[c] * x2;
                        acc[c][3] += wv[c] * x3;
                    }
                }
            }
        }
        __syncthreads();
    }

    const int oy = ty + prow;
    if (oy < H) {
        #pragma unroll
        for (int c = 0; c < 8; ++c) {
            int co = co0 + tco + c;
            if (co < C_out) {
                TA bv = (TA)bias[co];
                #pragma unroll
                for (int j = 0; j < 4; ++j) {
                    int ox = tx + pcol + j;
                    if (ox < W) {
                        TA v = acc[c][j] + bv;
                        if (RELU) v = v > (TA)0 ? v : (TA)0;
                        out[(((size_t)b * C_out + co) * H + oy) * W + ox] = v;
                    }
                }
            }
        }
    }
}

// ---------------------------------------------------------------------------
// cls5 screen in fp32 (R11-proven body; input now fp32 tower output).
// Tracks max + 2nd max; flags ambiguous (gap < TAU) (px,anchor) pairs.
// ---------------------------------------------------------------------------
#define CH5 8
__global__ __launch_bounds__(256, 2) void cls5_f32(
    const float* __restrict__ in, const float* __restrict__ wgt,
    const float* __restrict__ bias, float* __restrict__ scores,
    float* __restrict__ cls_id, unsigned char* __restrict__ flags,
    int H, int W, int level_off, int A_total, int b0)
{
    const int tilesX = (W + TLW - 1) / TLW;
    const int tx = (blockIdx.x % tilesX) * TLW;
    const int ty = (blockIdx.x / tilesX) * TLH;
    const int b  = blockIdx.y;
    const int a  = blockIdx.z;
    const int co0 = a * 80;
    const int tid = threadIdx.x;
    const int cog = tid >> 5;
    const int tco = cog * 10;
    const int tpx = tid & 31;
    const int prow = tpx >> 2;
    const int pcol = (tpx & 3) * 4;

    __shared__ __align__(16) float lw[CH5 * 9 * 80];
    __shared__ __align__(16) float li[CH5 * 10 * LIS];
    __shared__ float redM1[128 * 8];
    __shared__ float redM2[128 * 8];
    __shared__ int   redA [128 * 8];

    float acc[10][4];
    #pragma unroll
    for (int c = 0; c < 10; ++c)
        #pragma unroll
        for (int j = 0; j < 4; ++j) acc[c][j] = 0.f;

    for (int ch = 0; ch < CIN / CH5; ++ch) {
        const int ci0 = ch * CH5;
        for (int idx = tid; idx < CH5 * 9 * 80; idx += 256) {
            int r  = idx / 80;
            int co = idx % 80;
            lw[idx] = wgt[(size_t)(co0 + co) * (CIN * 9) + (size_t)ci0 * 9 + r];
        }
        for (int idx = tid; idx < CH5 * 10 * LIS; idx += 256) {
            int ci = idx / (10 * LIS);
            int rr = idx % (10 * LIS);
            int row = rr / LIS, col = rr % LIS;
            float v = 0.f;
            int iy = ty + row - 1, ix = tx + col - 1;
            if (col < TLW + 2 && iy >= 0 && iy < H && ix >= 0 && ix < W)
                v = in[(((size_t)b * CIN + ci0 + ci) * H + iy) * W + ix];
            li[idx] = v;
        }
        __syncthreads();
        #pragma unroll
        for (int ci = 0; ci < CH5; ++ci) {
            #pragma unroll
            for (int ky = 0; ky < 3; ++ky) {
                const float* ip = &li[ci * 10 * LIS + (prow + ky) * LIS + pcol];
                float ir[6];
                #pragma unroll
                for (int t = 0; t < 6; ++t) ir[t] = ip[t];
                #pragma unroll
                for (int kx = 0; kx < 3; ++kx) {
                    const float* wp = &lw[(ci * 9 + ky * 3 + kx) * 80 + tco];
                    float wv[10];
                    #pragma unroll
                    for (int c = 0; c < 10; ++c) wv[c] = wp[c];
                    float x0 = ir[kx], x1 = ir[kx + 1], x2 = ir[kx + 2], x3 = ir[kx + 3];
                    #pragma unroll
                    for (int c = 0; c < 10; ++c) {
                        acc[c][0] = fmaf(wv[c], x0, acc[c][0]);
                        acc[c][1] = fmaf(wv[c], x1, acc[c][1]);
                        acc[c][2] = fmaf(wv[c], x2, acc[c][2]);
                        acc[c][3] = fmaf(wv[c], x3, acc[c][3]);
                    }
                }
            }
        }
        __syncthreads();
    }

    #pragma unroll
    for (int j = 0; j < 4; ++j) {
        float m1 = acc[0][j] + bias[co0 + tco];
        float m2 = -3.0e38f;
        int am = tco;
        #pragma unroll
        for (int c = 1; c < 10; ++c) {
            float v = acc[c][j] + bias[co0 + tco + c];
            if (v > m1) { m2 = m1; m1 = v; am = tco + c; }
            else if (v > m2) { m2 = v; }
        }
        int p = prow * 16 + pcol + j;
        redM1[p * 8 + cog] = m1;
        redA [p * 8 + cog] = am;
        redM2[p * 8 + cog] = m2;
    }
    __syncthreads();
    if (tid < 128) {
        int p = tid;
        float m1 = redM1[p * 8]; int am = redA[p * 8]; float m2 = redM2[p * 8];
        #pragma unroll
        for (int t = 1; t < 8; ++t) {
            float rm1 = redM1[p * 8 + t];
            float rm2 = redM2[p * 8 + t];
            if (rm1 > m1) { m2 = fmaxf(m1, rm2); m1 = rm1; am = redA[p * 8 + t]; }
            else          { m2 = fmaxf(m2, rm1); }
        }
        int oy = ty + (p >> 4), ox = tx + (p & 15);
        if (oy < H && ox < W) {
            size_t oi = (size_t)(b0 + b) * A_total + level_off
                      + (size_t)(oy * W + ox) * 9 + a;
            scores[oi] = 1.f / (1.f + expf(-m1));
            cls_id[oi] = (float)am;
            flags[((size_t)b * H * W + oy * W + ox) * 9 + a] =
                (m1 - m2 < TAU) ? 1 : 0;
        }
    }
}

// ---------------------------------------------------------------------------
// flag compaction: one entry per flagged PIXEL (OR over anchors).
// ---------------------------------------------------------------------------
__global__ void zero_cnt(int* cnt) { if (threadIdx.x == 0) cnt[0] = 0; }

__global__ __launch_bounds__(256) void compact_flags(
    const unsigned char* __restrict__ flags, int* __restrict__ cnt,
    int* __restrict__ list, int HW, int Bc)
{
    int idx = blockIdx.x * 256 + threadIdx.x;
    if (idx >= Bc * HW) return;
    const unsigned char* f = flags + (size_t)idx * 9;
    int any = 0;
    #pragma unroll
    for (int a = 0; a < 9; ++a) any |= f[a];
    if (any) {
        int slot = atomicAdd(cnt, 1);
        if (slot < 32768) list[slot] = idx;   // idx = b*HW + px
    }
}

// ---------------------------------------------------------------------------
// fp64 full-tower fixup for flagged pixels. One block walks list entries
// (stride NSLOT). Per slot global scratch: S1 (81x256 f64), S2 (49x256 f64).
// Patch chain: feat 11x11 -> D1 9x9 -> D2 7x7 -> D3 5x5 -> D4 3x3 -> 720 lg.
// Outside-map patch cells are zero at every layer (matches SAME zero-pad).
// ---------------------------------------------------------------------------
__device__ void patch_conv64(
    const double* __restrict__ IN, double* __restrict__ OUT,
    int PWI, int PWO, const float* __restrict__ wgt,
    const float* __restrict__ bias,
    int H, int W, int y0, int x0, double* stg)
{
    const int tid = threadIdx.x;
    const int PIN = PWI * PWI, POUT = PWO * PWO;
    const int hwo = PWO >> 1, hwi = PWI >> 1;
    const int co = tid;                  // 256 threads = 256 channels
    for (int pb = 0; pb < POUT; pb += 8) {
        double acc[8];
        #pragma unroll
        for (int j = 0; j < 8; ++j) acc[j] = 0.0;
        for (int ch = 0; ch < 8; ++ch) {
            const int ci0 = ch * 32;
            __syncthreads();
            for (int i = tid; i < PIN * 32; i += 256) {
                int ci = i / PIN, r = i % PIN;
                stg[ci * PIN + r] = IN[(size_t)r * 256 + ci0 + ci];
            }
            __syncthreads();
            const float* wr = wgt + (size_t)co * K9 + ci0 * 9;
            for (int ci = 0; ci < 32; ++ci) {
                #pragma unroll
                for (int t = 0; t < 9; ++t) {
                    double w = (double)wr[ci * 9 + t];
                    int ky = t / 3 - 1, kx = t % 3 - 1;
                    #pragma unroll
                    for (int j = 0; j < 8; ++j) {
                        int px = pb + j;
                        int dyo = px / PWO - hwo, dxo = px % PWO - hwo;
                        int r = (dyo + ky + hwi) * PWI + (dxo + kx + hwi);
                        // px >= POUT may read stray (in-bounds of stg buffer,
                        // discarded at write)
                        int rr = r < 0 ? 0 : (r >= PIN ? PIN - 1 : r);
                        acc[j] += w * stg[ci * PIN + rr];
                    }
                }
            }
        }
        #pragma unroll
        for (int j = 0; j < 8; ++j) {
            int px = pb + j;
            if (px < POUT) {
                int dyo = px / PWO - hwo, dxo = px % PWO - hwo;
                int gy = y0 + dyo, gx = x0 + dxo;
                double v = 0.0;
                if (gy >= 0 && gy < H && gx >= 0 && gx < W) {
                    v = acc[j] + (double)bias[co];
                    v = v > 0.0 ? v : 0.0;
                }
                OUT[(size_t)px * 256 + co] = v;
            }
        }
    }
}

__global__ __launch_bounds__(256) void fixup_tower(
    const float* __restrict__ feat,
    const float* __restrict__ w1, const float* __restrict__ b1,
    const float* __restrict__ w2, const float* __restrict__ b2,
    const float* __restrict__ w3, const float* __restrict__ b3,
    const float* __restrict__ w4, const float* __restrict__ b4,
    const float* __restrict__ w5, const float* __restrict__ b5,
    const int* __restrict__ cnt, const int* __restrict__ list,
    double* __restrict__ slots,
    float* __restrict__ scores, float* __restrict__ cls_id,
    int H, int W, int level_off, int A_total, int b0)
{
    const int tid = threadIdx.x;
    __shared__ double stg[121 * 32];     // 30.2 KB (layer-1 size; reused)
    __shared__ double lg[720];           // 5.8 KB

    int n = cnt[0];
    if (n > 32768) n = 32768;
    double* S1 = slots + (size_t)blockIdx.x * SLOT_DBL;       // 81*256
    double* S2 = S1 + 81 * 256;                               // 49*256

    for (int e = blockIdx.x; e < n; e += NSLOT) {
        int ent = list[e];
        int b  = ent / (H * W);
        int px = ent % (H * W);
        int y0 = px / W, x0 = px % W;

        // ---- layer 1: feat fp32 -> S1 (9x9x256), input patch 11x11 ------
        {
            const int co = tid;
            for (int pb = 0; pb < 81; pb += 8) {
                double acc[8];
                #pragma unroll
                for (int j = 0; j < 8; ++j) acc[j] = 0.0;
                for (int ch = 0; ch < 8; ++ch) {
                    const int ci0 = ch * 32;
                    __syncthreads();
                    for (int i = tid; i < 121 * 32; i += 256) {
                        int ci = i / 121, r = i % 121;
                        int iy = y0 + r / 11 - 5, ix = x0 + r % 11 - 5;
                        double v = 0.0;
                        if (iy >= 0 && iy < H && ix >= 0 && ix < W)
                            v = (double)feat[(((size_t)b * CIN + ci0 + ci) * H
                                              + iy) * W + ix];
                        stg[ci * 121 + r] = v;
                    }
                    __syncthreads();
                    const float* wr = w1 + (size_t)co * K9 + ci0 * 9;
                    for (int ci = 0; ci < 32; ++ci) {
                        #pragma unroll
                        for (int t = 0; t < 9; ++t) {
                            double w = (double)wr[ci * 9 + t];
                            int ky = t / 3 - 1, kx = t % 3 - 1;
                            #pragma unroll
                            for (int j = 0; j < 8; ++j) {
                                int p2 = pb + j;
                                int dyo = p2 / 9 - 4, dxo = p2 % 9 - 4;
                                int r = (dyo + ky + 5) * 11 + (dxo + kx + 5);
                                int rr = r < 0 ? 0 : (r >= 121 ? 120 : r);
                                acc[j] += w * stg[ci * 121 + rr];
                            }
                        }
                    }
                }
                #pragma unroll
                for (int j = 0; j < 8; ++j) {
                    int p2 = pb + j;
                    if (p2 < 81) {
                        int dyo = p2 / 9 - 4, dxo = p2 % 9 - 4;
                        int gy = y0 + dyo, gx = x0 + dxo;
                        double v = 0.0;
                        if (gy >= 0 && gy < H && gx >= 0 && gx < W) {
                            v = acc[j] + (double)b1[co];
                            v = v > 0.0 ? v : 0.0;
                        }
                        S1[(size_t)p2 * 256 + co] = v;
                    }
                }
            }
        }
        __syncthreads();
        // ---- layers 2..4 ------------------------------------------------
        patch_conv64(S1, S2, 9, 7, w2, b2, H, W, y0, x0, stg);
        __syncthreads();
        patch_conv64(S2, S1, 7, 5, w3, b3, H, W, y0, x0, stg);
        __syncthreads();
        patch_conv64(S1, S2, 5, 3, w4, b4, H, W, y0, x0, stg);
        __syncthreads();
        // ---- layer 5: S2 (3x3x256) -> 720 logits ------------------------
        for (int c5 = tid; c5 < 720; c5 += 256) {
            const float* wr = w5 + (size_t)c5 * K9;
            double s = (double)b5[c5];
            for (int k = 0; k < K9; ++k) {
                int ci = k / 9, t = k % 9;
                s += (double)wr[k] * S2[(size_t)t * 256 + ci];
            }
            lg[c5] = s;
        }
        __syncthreads();
        if (tid < 9) {
            int a = tid;
            double m = lg[a * 80]; int am = 0;
            for (int c = 1; c < 80; ++c) {
                double v = lg[a * 80 + c];
                if (v > m) { m = v; am = c; }
            }
            size_t oi = (size_t)(b0 + b) * A_total + level_off
                      + (size_t)px * 9 + a;
            scores[oi] = (float)(1.0 / (1.0 + exp(-m)));
            cls_id[oi] = (float)am;
        }
        __syncthreads();
    }
}

// ---------------------------------------------------------------------------
__global__ void boxes_ep(const float* __restrict__ reg5, float* __restrict__ boxes,
                         int H, int W, int level_off, int A_total, float stride,
                         int b0, int Bc)
{
    int idx = blockIdx.x * 256 + threadIdx.x;
    int total = Bc * H * W * 9;
    if (idx >= total) return;
    int a = idx % 9; int rest = idx / 9;
    int x = rest % W; rest /= W;
    int y = rest % H; int b = rest / H;

    float base = 4.f * stride;
    float scale = exp2f((float)(a % 3) * (1.f / 3.f));
    int ri = a / 3;
    float sr = (ri == 0) ? 0.70710678118654752f : (ri == 1 ? 1.f : 1.41421356237309505f);
    float wa = base * scale / sr;
    float ha = base * scale * sr;
    float cx = (x + 0.5f) * stride, cy = (y + 0.5f) * stride;

    size_t cs = (size_t)H * W;
    const float* rp = reg5 + (((size_t)b * 36 + a * 4) * H + y) * W + x;
    float d0 = rp[0], d1 = rp[cs], d2 = rp[2 * cs], d3 = rp[3 * cs];

    float pcx = cx + d0 * 0.1f * wa;
    float pcy = cy + d1 * 0.1f * ha;
    float pw  = expf(d2 * 0.2f) * wa;
    float ph  = expf(d3 * 0.2f) * ha;

    size_t oi = ((size_t)(b0 + b) * A_total + level_off
               + (size_t)(y * W + x) * 9 + a) * 4;
    boxes[oi + 0] = pcx - 0.5f * pw;
    boxes[oi + 1] = pcy - 0.5f * ph;
    boxes[oi + 2] = pcx + 0.5f * pw;
    boxes[oi + 3] = pcy + 0.5f * ph;
}

// ---------------------------------------------------------------------------
extern "C" void kernel_launch(void* const* d_in, const int* in_sizes, int n_in,
                              void* d_out, int out_size, void* d_ws, size_t ws_size,
                              hipStream_t stream)
{
    const float* feats[5];
    for (int i = 0; i < 5; ++i) feats[i] = (const float*)d_in[i];
    const float* cw[5]; const float* cb[5];
    const float* rw[5]; const float* rb[5];
    for (int i = 0; i < 5; ++i) {
        cw[i] = (const float*)d_in[5 + 2 * i];
        cb[i] = (const float*)d_in[6 + 2 * i];
        rw[i] = (const float*)d_in[15 + 2 * i];
        rb[i] = (const float*)d_in[16 + 2 * i];
    }

    const int A_total = 49104;
    float* scores = (float*)d_out;
    float* cls_id = scores + (size_t)8 * A_total;
    float* boxes  = scores + (size_t)2 * 8 * A_total;

    const int   Hs[5]      = {64, 32, 16, 8, 4};
    const float strides[5] = {8.f, 16.f, 32.f, 64.f, 128.f};
    const int   offs[5]    = {0, 36864, 46080, 48384, 48960};

    // ws: [flags 128K][cnt 256B][list 128K][slots NSLOT*260K][activations]
    const size_t flagRes = 131072;
    const size_t cntRes  = 256;
    const size_t listRes = 32768 * 4;
    const size_t slotRes = (size_t)NSLOT * SLOT_DBL * 8;
    unsigned char* flags = (unsigned char*)d_ws;
    int*    cnt   = (int*)((char*)d_ws + flagRes);
    int*    list  = (int*)((char*)d_ws + flagRes + cntRes);
    double* slots = (double*)((char*)d_ws + flagRes + cntRes + listRes);
    size_t fixed  = flagRes + cntRes + listRes + slotRes;
    char*  actBase  = (char*)d_ws + fixed;
    size_t actBytes = ws_size > fixed ? ws_size - fixed : 0;

    // ---------------- cls tower (fp32 conv x4 + fp32 cls5 + fp64 fixup) ----
    for (int l = 0; l < 5; ++l) {
        int H = Hs[l], W = Hs[l];
        int HW = H * W;
        size_t perb = (size_t)CIN * HW;
        int Bc = 8;
        while (Bc > 1 && 2ull * Bc * perb * 4 > actBytes) Bc >>= 1;
        float* F0 = (float*)actBase;
        float* F1 = F0 + (size_t)Bc * perb;
        int tiles = ((W + TLW - 1) / TLW) * ((H + TLH - 1) / TLH);
        for (int b0 = 0; b0 < 8; b0 += Bc) {
            const float* fin = feats[l] + (size_t)b0 * perb;
            dim3 g(tiles, Bc, 4);
            conv_tile<float, float, 8, true><<<g, 256, 0, stream>>>(fin, cw[0], cb[0], F0, H, W, 256);
            conv_tile<float, float, 8, true><<<g, 256, 0, stream>>>(F0,  cw[1], cb[1], F1, H, W, 256);
            conv_tile<float, float, 8, true><<<g, 256, 0, stream>>>(F1,  cw[2], cb[2], F0, H, W, 256);
            conv_tile<float, float, 8, true><<<g, 256, 0, stream>>>(F0,  cw[3], cb[3], F1, H, W, 256);
            dim3 g5(tiles, Bc, 9);
            cls5_f32<<<g5, 256, 0, stream>>>(F1, cw[4], cb[4], scores, cls_id,
                                             flags, H, W, offs[l], A_total, b0);
            zero_cnt<<<1, 64, 0, stream>>>(cnt);
            compact_flags<<<(Bc * HW + 255) / 256, 256, 0, stream>>>(
                flags, cnt, list, HW, Bc);
            fixup_tower<<<NSLOT, 256, 0, stream>>>(
                fin, cw[0], cb[0], cw[1], cb[1], cw[2], cb[2], cw[3], cb[3],
                cw[4], cb[4], cnt, list, slots, scores, cls_id,
                H, W, offs[l], A_total, b0);
        }
    }

    // ---------------- reg tower (fp32, proven) ------------------------------
    for (int l = 0; l < 5; ++l) {
        int H = Hs[l], W = Hs[l];
        size_t perb = (size_t)CIN * H * W;
        int Br = 8;
        while (Br > 1 && 2ull * Br * perb * 4 > actBytes) Br >>= 1;
        float* F0 = (float*)actBase;
        float* F1 = F0 + (size_t)Br * perb;
        int tiles = ((W + TLW - 1) / TLW) * ((H + TLH - 1) / TLH);
        for (int b0 = 0; b0 < 8; b0 += Br) {
            dim3 g(tiles, Br, 4);
            const float* fin = feats[l] + (size_t)b0 * perb;
            conv_tile<float, float, 8, true><<<g, 256, 0, stream>>>(fin, rw[0], rb[0], F0, H, W, 256);
            conv_tile<float, float, 8, true><<<g, 256, 0, stream>>>(F0,  rw[1], rb[1], F1, H, W, 256);
            conv_tile<float, float, 8, true><<<g, 256, 0, stream>>>(F1,  rw[2], rb[2], F0, H, W, 256);
            conv_tile<float, float, 8, true><<<g, 256, 0, stream>>>(F0,  rw[3], rb[3], F1, H, W, 256);
            dim3 gr(tiles, Br, 1);
            conv_tile<float, float, 8, false><<<gr, 256, 0, stream>>>(F1, rw[4], rb[4], F0, H, W, 36);
            int total = Br * H * W * 9;
            boxes_ep<<<(total + 255) / 256, 256, 0, stream>>>(F0, boxes, H, W,
                                                              offs[l], A_total,
                                                              strides[l], b0, Br);
        }
    }
}